// Round 1
// baseline (1645.251 us; speedup 1.0000x reference)
//
#include <hip/hip_runtime.h>
#include <hip/hip_fp16.h>

// DNCClassifier: the DNC memory machinery is dead code (inputs built with the
// initial zero read vector; output depends only on the LSTM h). Implement:
//   gates_t = x_t @ W_ih[:, :27].T + (b_ih + b_hh) + h @ W_hh.T
//   i,f,g,o = split(gates); c = sig(f)*c + sig(i)*tanh(g); h = sig(o)*tanh(c)
//   out = h_T @ W_fc.T + b_fc
// Sizes: B=128, T=512, IN=27, H=256 (4H=1024), OUT=128.
//
// Plan:
//  prep_w : convert W_hh -> fp16 in scan-friendly interleaved layout + bias4
//  prep_p : P[t,b,u,g] = x-part of gate preactivations, fp16 (128 MB in ws)
//  scan_k : persistent per-batch block (grid=128, block=256). Each thread owns
//           unit u's 4 gate rows: 116 h2 of each row in VGPRs (464 regs),
//           last 12 h2/row staged in LDS. 512 fdot2/thread/step.

typedef _Float16 h2t __attribute__((ext_vector_type(2)));

#if defined(__has_builtin)
#  if __has_builtin(__builtin_amdgcn_fdot2)
#    define HAVE_FDOT2 1
#  endif
#endif

__device__ __forceinline__ h2t bc2(unsigned int v) {
  union { unsigned int u; h2t h; } x; x.u = v; return x.h;
}
__device__ __forceinline__ unsigned int pk(float a, float b) {
  union { h2t h; unsigned int u; } x;
  x.h[0] = (_Float16)a; x.h[1] = (_Float16)b;
  return x.u;
}
__device__ __forceinline__ float fdot2f(h2t a, h2t b, float c) {
#ifdef HAVE_FDOT2
  return __builtin_amdgcn_fdot2(a, b, c, false);
#else
  return c + (float)a[0] * (float)b[0] + (float)a[1] * (float)b[1];
#endif
}
__device__ __forceinline__ float sigmf_(float x) {
  return 1.f / (1.f + __expf(-x));
}
__device__ __forceinline__ float tanhf_(float x) {
  float xc = fminf(15.f, fmaxf(-15.f, x));
  float e = __expf(2.f * xc);
  return (e - 1.f) / (e + 1.f);
}

// ---- workspace layout (bytes) ----
// P      : [t*128+b][u*4+g] halves, 512*128*1024*2 = 134,217,728
// Wscan  : uint4[(g*30+q)*256+u], q<30 (q=29 pad), h2 k2=4q+e (valid k2<116)
// Wtail  : uint4[(g*3+qq)*256+u], h2 k2=116+4qq+e
// bias4  : float[u*4+g] = b_ih[g*256+u]+b_hh[g*256+u]
#define WS_P_OFF      0ull
#define WS_WSCAN_OFF  134217728ull
#define WS_WTAIL_OFF  134709248ull
#define WS_BIAS_OFF   134758400ull
#define WS_NEED       134762496ull

__global__ void prep_w(const float* __restrict__ W_hh,
                       const float* __restrict__ b_ih,
                       const float* __restrict__ b_hh,
                       unsigned char* __restrict__ ws) {
  int idx = blockIdx.x * 256 + threadIdx.x;
  if (idx < 122880) {                       // Wscan: 4*30*256*4 uints
    int e = idx & 3; int rest = idx >> 2;   // rest = (g*30+q)*256+u
    int u = rest & 255; int gq = rest >> 8;
    int g = gq / 30, q = gq - 30 * g;
    int k2 = 4 * q + e;
    unsigned int v = 0u;
    if (k2 < 116) {
      int r = g * 256 + u;
      v = pk(W_hh[r * 256 + 2 * k2], W_hh[r * 256 + 2 * k2 + 1]);
    }
    ((unsigned int*)(ws + WS_WSCAN_OFF))[idx] = v;
  } else if (idx < 122880 + 12288) {        // Wtail: 4*3*256*4 uints
    int j = idx - 122880;
    int e = j & 3; int rest = j >> 2;
    int u = rest & 255; int gq = rest >> 8;
    int g = gq / 3, qq = gq - 3 * g;
    int k2 = 116 + 4 * qq + e;
    int r = g * 256 + u;
    ((unsigned int*)(ws + WS_WTAIL_OFF))[j] =
        pk(W_hh[r * 256 + 2 * k2], W_hh[r * 256 + 2 * k2 + 1]);
  } else if (idx < 122880 + 12288 + 1024) { // bias4
    int j = idx - 135168;
    int g = j & 3, u = j >> 2;
    ((float*)(ws + WS_BIAS_OFF))[j] = b_ih[g * 256 + u] + b_hh[g * 256 + u];
  }
}

// P[t,b,u,g] = sum_c x[b,t,c] * W_ih[g*256+u, c], c<27.  1024 blocks x 64 pairs.
__global__ __launch_bounds__(256) void prep_p(const float* __restrict__ x,
                                              const float* __restrict__ W_ih,
                                              unsigned char* __restrict__ ws) {
  __shared__ unsigned int sX[16];
  const int u = threadIdx.x;
  unsigned int wih[4][14];
#pragma unroll
  for (int g = 0; g < 4; ++g) {
    const float* row = W_ih + (size_t)(g * 256 + u) * 47;
#pragma unroll
    for (int j = 0; j < 14; ++j) {
      float a = row[2 * j];
      float b = (2 * j + 1 < 27) ? row[2 * j + 1] : 0.f;
      wih[g][j] = pk(a, b);
    }
  }
  uint2* Pout = (uint2*)(ws + WS_P_OFF);
#pragma unroll 1
  for (int p = 0; p < 64; ++p) {
    int idx = blockIdx.x * 64 + p;
    int t = idx >> 7, b = idx & 127;
    __syncthreads();                      // protect sX reuse across pairs
    if (u < 14) {
      const float* xr = x + ((size_t)b * 512 + t) * 27;
      float a = xr[2 * u];
      float bb = (2 * u + 1 < 27) ? xr[2 * u + 1] : 0.f;
      sX[u] = pk(a, bb);
    }
    __syncthreads();
    float acc[4] = {0.f, 0.f, 0.f, 0.f};
#pragma unroll
    for (int j = 0; j < 14; ++j) {
      h2t xx = bc2(sX[j]);
#pragma unroll
      for (int g = 0; g < 4; ++g) acc[g] = fdot2f(bc2(wih[g][j]), xx, acc[g]);
    }
    uint2 o;
    o.x = pk(acc[0], acc[1]);
    o.y = pk(acc[2], acc[3]);
    Pout[(size_t)idx * 256 + u] = o;
  }
}

// Persistent LSTM scan: one block per batch element, 256 threads (4 waves,
// 1 wave/SIMD -> up to 512 VGPRs/wave). Thread u owns gate rows
// {u, 256+u, 512+u, 768+u}; k2 0..115 in VGPRs, k2 116..127 in LDS (private).
__global__ __launch_bounds__(256, 1) void scan_k(
    const unsigned char* __restrict__ ws, const float* __restrict__ W_fc,
    const float* __restrict__ b_fc, float* __restrict__ out) {
  __shared__ __align__(16) unsigned int sH[128];  // h as 128 half2
  __shared__ uint4 sTail[256 * 13];               // 53,248 B, stride 13 quads
  __shared__ __align__(16) float sHF[256];        // final h fp32 for head
  const int u = threadIdx.x;
  const int b = blockIdx.x;

  // --- load resident weights into VGPRs ---
  unsigned int wreg[4][116];
  {
    const uint4* wsc = (const uint4*)(ws + WS_WSCAN_OFF);
#pragma unroll
    for (int g = 0; g < 4; ++g)
#pragma unroll
      for (int q = 0; q < 29; ++q) {
        uint4 v = wsc[(g * 30 + q) * 256 + u];
        wreg[g][4 * q + 0] = v.x;
        wreg[g][4 * q + 1] = v.y;
        wreg[g][4 * q + 2] = v.z;
        wreg[g][4 * q + 3] = v.w;
      }
  }
  // --- stage tail weights into (thread-private) LDS ---
  {
    const uint4* wt = (const uint4*)(ws + WS_WTAIL_OFF);
#pragma unroll
    for (int g = 0; g < 4; ++g)
#pragma unroll
      for (int qq = 0; qq < 3; ++qq)
        sTail[u * 13 + g * 3 + qq] = wt[(g * 3 + qq) * 256 + u];
  }
  const float4 bias = ((const float4*)(ws + WS_BIAS_OFF))[u];
  if (u < 64) ((uint2*)sH)[u] = make_uint2(0u, 0u);  // h_0 = 0

  const uint2* Pbuf = (const uint2*)(ws + WS_P_OFF);
  uint2 pP = Pbuf[(size_t)b * 256 + u];  // t=0 prefetch
  float c = 0.f, hval = 0.f;
  __syncthreads();

#pragma unroll 1
  for (int t = 0; t < 512; ++t) {
    const int tn = (t + 1 < 512) ? (t + 1) : 511;
    uint2 pPn = Pbuf[((size_t)tn * 128 + b) * 256 + u];  // next-step prefetch

    float acc[4] = {0.f, 0.f, 0.f, 0.f};
    const uint4* sH4 = (const uint4*)sH;
#pragma unroll
    for (int q = 0; q < 29; ++q) {  // k2 0..115 (VGPR weights)
      uint4 hq = sH4[q];
      h2t hh[4] = {bc2(hq.x), bc2(hq.y), bc2(hq.z), bc2(hq.w)};
#pragma unroll
      for (int e = 0; e < 4; ++e)
#pragma unroll
        for (int g = 0; g < 4; ++g)
          acc[g] = fdot2f(bc2(wreg[g][4 * q + e]), hh[e], acc[g]);
    }
#pragma unroll
    for (int q = 29; q < 32; ++q) {  // k2 116..127 (LDS tail weights)
      uint4 hq = sH4[q];
      h2t hh[4] = {bc2(hq.x), bc2(hq.y), bc2(hq.z), bc2(hq.w)};
#pragma unroll
      for (int g = 0; g < 4; ++g) {
        uint4 tw = sTail[u * 13 + g * 3 + (q - 29)];
        acc[g] = fdot2f(bc2(tw.x), hh[0], acc[g]);
        acc[g] = fdot2f(bc2(tw.y), hh[1], acc[g]);
        acc[g] = fdot2f(bc2(tw.z), hh[2], acc[g]);
        acc[g] = fdot2f(bc2(tw.w), hh[3], acc[g]);
      }
    }
    __syncthreads();  // all sH reads done before overwrite

    // pointwise LSTM update (all 256 threads, one hidden unit each)
    h2t p01 = bc2(pP.x), p23 = bc2(pP.y);
    float gi = acc[0] + bias.x + (float)p01[0];
    float gf = acc[1] + bias.y + (float)p01[1];
    float gg = acc[2] + bias.z + (float)p23[0];
    float go = acc[3] + bias.w + (float)p23[1];
    c = sigmf_(gf) * c + sigmf_(gi) * tanhf_(gg);
    hval = sigmf_(go) * tanhf_(c);
    ((_Float16*)sH)[u] = (_Float16)hval;
    pP = pPn;
    __syncthreads();  // h_{t+1} visible for next dot
  }

  // --- classifier head on final h ---
  sHF[u] = hval;
  __syncthreads();
  if (u < 128) {
    const float4* wrow = (const float4*)(W_fc + (size_t)u * 256);
    float a = b_fc[u];
#pragma unroll 8
    for (int q = 0; q < 64; ++q) {
      float4 w = wrow[q];
      float4 hh = ((const float4*)sHF)[q];
      a += w.x * hh.x + w.y * hh.y + w.z * hh.z + w.w * hh.w;
    }
    out[(size_t)b * 128 + u] = a;
  }
}

extern "C" void kernel_launch(void* const* d_in, const int* in_sizes, int n_in,
                              void* d_out, int out_size, void* d_ws,
                              size_t ws_size, hipStream_t stream) {
  const float* x    = (const float*)d_in[0];
  // d_in[1] = input_lengths: unused by the reference
  const float* W_ih = (const float*)d_in[2];
  const float* W_hh = (const float*)d_in[3];
  const float* b_ih = (const float*)d_in[4];
  const float* b_hh = (const float*)d_in[5];
  // d_in[6] = W_xi, d_in[7] = b_xi: dead code in the reference
  const float* W_fc = (const float*)d_in[8];
  const float* b_fc = (const float*)d_in[9];
  unsigned char* ws = (unsigned char*)d_ws;

  if (ws_size < WS_NEED) {
    // Failure signature: output stays zero -> absmax == max|ref| (~0.1875).
    return;
  }

  prep_w<<<532, 256, 0, stream>>>(W_hh, b_ih, b_hh, ws);
  prep_p<<<1024, 256, 0, stream>>>(x, W_ih, ws);
  scan_k<<<128, 256, 0, stream>>>(ws, W_fc, b_fc, (float*)d_out);
}